// Round 9
// baseline (264.034 us; speedup 1.0000x reference)
//
#include <hip/hip_runtime.h>

typedef __attribute__((ext_vector_type(8))) short s16x8;
typedef __attribute__((ext_vector_type(4))) short s16x4;
typedef __attribute__((ext_vector_type(4))) float f32x4;
typedef __attribute__((ext_vector_type(8))) __bf16 bf16x8;
typedef __attribute__((ext_vector_type(2))) unsigned u32x2;
typedef __attribute__((ext_vector_type(2))) unsigned long long u64x2;

// fp32 -> bf16 round-to-nearest-even
__device__ __forceinline__ short f2b(float f) {
  unsigned u = __float_as_uint(f);
  u += 0x7fffu + ((u >> 16) & 1u);
  return (short)(u >> 16);
}

// pack two fp32 -> two bf16 (truncate) in ONE v_perm_b32
__device__ __forceinline__ unsigned pkb(float lo, float hi) {
  return __builtin_amdgcn_perm(__float_as_uint(hi), __float_as_uint(lo),
                               0x07060302u);
}

__device__ __forceinline__ f32x4 mfma32(s16x8 a, s16x8 b, f32x4 c) {
  return __builtin_amdgcn_mfma_f32_16x16x32_bf16(
      __builtin_bit_cast(bf16x8, a), __builtin_bit_cast(bf16x8, b), c, 0, 0, 0);
}

#if __has_builtin(__builtin_amdgcn_mfma_f32_16x16x16bf16_1k)
#define HAVE_MFMA16 1
__device__ __forceinline__ f32x4 mfma16(s16x4 a, s16x4 b, f32x4 c) {
  return __builtin_amdgcn_mfma_f32_16x16x16bf16_1k(a, b, c, 0, 0, 0);
}
#else
#define HAVE_MFMA16 0
// repack P (S^T C-layout regs, k=16j+quad*4+r) into 16x16x32 A-frag (k=quad*8+c)
__device__ __forceinline__ s16x8 repack(s16x4 pa, s16x4 pb, int quad, int ln15) {
  unsigned long long a = __builtin_bit_cast(unsigned long long, pa);
  unsigned long long bq = __builtin_bit_cast(unsigned long long, pb);
  int srcLo = ((quad & 1) << 5) | ln15;
  unsigned long long loa = __shfl(a, srcLo);
  unsigned long long lob = __shfl(bq, srcLo);
  unsigned long long hia = __shfl(a, srcLo + 16);
  unsigned long long hib = __shfl(bq, srcLo + 16);
  u64x2 t;
  t[0] = quad < 2 ? loa : lob;
  t[1] = quad < 2 ? hia : hib;
  return __builtin_bit_cast(s16x8, t);
}
#endif

// ---------------- convert fp32 -> bf16 (x, Wq|Wk|Wv concat, Wo) ----------------
__global__ __launch_bounds__(256) void convert_all(
    const float* __restrict__ x, const float* __restrict__ wq,
    const float* __restrict__ wk, const float* __restrict__ wv,
    const float* __restrict__ wo, short* __restrict__ xb,
    short* __restrict__ wqkvb, short* __restrict__ wob) {
  size_t i4 = ((size_t)blockIdx.x * 256 + threadIdx.x) * 4;
  const float* src;
  short* dst;
  size_t off;
  if (i4 < 8388608) {
    src = x; dst = xb; off = i4;
  } else if (i4 < 9437184) {
    src = wq; dst = wqkvb; off = i4 - 8388608;
  } else if (i4 < 10485760) {
    src = wk; dst = wqkvb + 1048576; off = i4 - 9437184;
  } else if (i4 < 11534336) {
    src = wv; dst = wqkvb + 2097152; off = i4 - 10485760;
  } else {
    src = wo; dst = wob; off = i4 - 11534336;
  }
  float4 f = *(const float4*)(src + off);
  s16x4 o;
  o[0] = f2b(f.x); o[1] = f2b(f.y); o[2] = f2b(f.z); o[3] = f2b(f.w);
  *(s16x4*)(dst + off) = o;
}

// ---------------- GEMM: C[M,N] = A[M,K] * B[N,K]^T -------------------------
// 64x128 tiles, BK=64, 4 waves (wm 2x wn 2), per-wave 32x64, acc[2][4]=32 VGPR.
// Small accumulator -> whole kernel fits <=85 VGPR -> __launch_bounds__(256,6)
// -> 6 blocks/CU resident (24 waves/CU). QKV grid 3072 = exactly 2 rounds of
// 6/CU (100% packing, was 1.5 rounds at 75%); proj grid 1024 = 4/CU single
// round (2x parallelism vs 128^2's 512 blocks). LDS 24.6KB: lA 64x64 +
// lB 128x64, single-buffered 2-barrier loop (m97 family). Staging via
// global_load_lds, XOR granule swizzle both-sides (rule #21): source granule
// pre-swizzled, LDS linear, read XOR key ln15&7 (thread-constant, folds into
// base). XCD-contiguous remap kept (grids divisible by 8).
__device__ __forceinline__ void stage_tile(const short* __restrict__ A,
                                           const short* __restrict__ B, int K,
                                           int m0, int n0, int k0, short* lA,
                                           short* lB, int wid, int lane) {
  // A: 64x64 shorts = 512 granules(16B); B: 128x64 = 1024; 1536 total = 6/thr.
#pragma unroll
  for (int i = 0; i < 6; ++i) {
    int g0 = i * 256 + wid * 64;  // wave-uniform granule base (A/B split at 512)
    int g = g0 + lane;
    const short* src;
    short* dst;
    if (g0 < 512) {
      int row = g >> 3;
      int sg = (g & 7) ^ (row & 7);
      src = A + (size_t)(m0 + row) * K + k0 + sg * 8;
      dst = lA + g0 * 8;
    } else {
      int gb = g - 512;
      int row = gb >> 3;
      int sg = (gb & 7) ^ (row & 7);
      src = B + (size_t)(n0 + row) * K + k0 + sg * 8;
      dst = lB + (g0 - 512) * 8;
    }
    __builtin_amdgcn_global_load_lds(
        (const __attribute__((address_space(1))) void*)src,
        (__attribute__((address_space(3))) void*)dst, 16, 0, 0);
  }
}

// EPI 0: scatter QKV -> Q (pre-scaled by log2e/8), K, V, all bf16 [B,H,T,D],
//        via LDS-coalesced epilogue (16B contiguous stores).
// EPI 1: fp32 direct store.
template <int EPI>
__global__ __launch_bounds__(256, 6) void gemm_bt(
    const short* __restrict__ A, const short* __restrict__ Bw,
    float* __restrict__ outf, short* __restrict__ qkv,
    int M, int N, int K) {
  // lA (8KB) + lB (16KB) for K-loop; epilogue overlays lC 64x132 (16.9KB)
  __shared__ __align__(16) char smem[24576];
  short* lA = (short*)smem;
  short* lB = lA + 4096;
  const int tid = threadIdx.x;
  const int lane = tid & 63, wid = tid >> 6;
  const int quad = lane >> 4, ln15 = lane & 15;
  const int kx = ln15 & 7;  // staging-swizzle read key
  const int wm = wid & 1, wn = wid >> 1;
  // XCD-contiguous tile remap (bijective; nwg divisible by 8)
  const int gx = (int)gridDim.x;
  const int lin = (int)blockIdx.y * gx + (int)blockIdx.x;
  const int cpx = (gx * (int)gridDim.y) >> 3;
  const int t = (lin & 7) * cpx + (lin >> 3);
  const int m0 = (t / gx) * 64, n0 = (t % gx) * 128;

  f32x4 acc[2][4] = {};

  stage_tile(A, Bw, K, m0, n0, 0, lA, lB, wid, lane);

  const int nk = K >> 6;
  for (int kt = 0; kt < nk; ++kt) {
    __syncthreads();
#pragma unroll
    for (int h = 0; h < 2; ++h) {
      s16x8 af[2], bf[4];
#pragma unroll
      for (int i = 0; i < 2; ++i)
        af[i] = *(const s16x8*)&lA[(wm * 32 + i * 16 + ln15) * 64 +
                                   (((h << 2) + quad) ^ kx) * 8];
#pragma unroll
      for (int j = 0; j < 4; ++j)
        bf[j] = *(const s16x8*)&lB[(wn * 64 + j * 16 + ln15) * 64 +
                                   (((h << 2) + quad) ^ kx) * 8];
#pragma unroll
      for (int i = 0; i < 2; ++i)
#pragma unroll
        for (int j = 0; j < 4; ++j)
          acc[i][j] = mfma32(af[i], bf[j], acc[i][j]);
    }
    __syncthreads();
    if (kt + 1 < nk)
      stage_tile(A, Bw, K, m0, n0, (kt + 1) << 6, lA, lB, wid, lane);
  }

  if (EPI == 1) {
#pragma unroll
    for (int i = 0; i < 2; ++i)
#pragma unroll
      for (int j = 0; j < 4; ++j)
#pragma unroll
        for (int r = 0; r < 4; ++r) {
          int m = m0 + wm * 32 + i * 16 + quad * 4 + r;
          int n = n0 + wn * 64 + j * 16 + ln15;
          outf[(size_t)m * N + n] = acc[i][j][r];
        }
  } else {
    const float QSC = 0.18033688f;  // (1/sqrt(64)) * log2(e), folded into Q
    const int which = n0 >> 10;     // n0 mult of 128: tile within one of Q/K/V
    const float sf = (which == 0) ? QSC : 1.0f;
    short* lC = (short*)smem;
    __syncthreads();  // all waves done with lA/lB ds_reads
#pragma unroll
    for (int i = 0; i < 2; ++i)
#pragma unroll
      for (int j = 0; j < 4; ++j) {
        int mm = wm * 32 + i * 16 + quad * 4;
        int nn = wn * 64 + j * 16 + ln15;
#pragma unroll
        for (int r = 0; r < 4; ++r)
          lC[(mm + r) * 132 + nn] = f2b(acc[i][j][r] * sf);
      }
    __syncthreads();
    short* outb = qkv + (size_t)which * 8388608;
#pragma unroll
    for (int r0 = 0; r0 < 4; ++r0) {
      int m = r0 * 16 + (tid >> 4);
      int ncol = (tid & 15) * 8;
      s16x4 lo = *(const s16x4*)&lC[m * 132 + ncol];
      s16x4 hi = *(const s16x4*)&lC[m * 132 + ncol + 4];
      s16x8 v8;
#pragma unroll
      for (int z = 0; z < 4; ++z) { v8[z] = lo[z]; v8[4 + z] = hi[z]; }
      int n = n0 + ncol;
      int mg = m0 + m;
      int bidx = mg >> 11, tt = mg & 2047;
      int hh = (n >> 6) & 15, d0 = n & 63;
      *(s16x8*)&outb[(size_t)((((bidx << 4) + hh) << 11) + tt) * 64 + d0] = v8;
    }
  }
}

// ---------------- flash attention, S^T form, fixed-max ----------------------
// EXACT r3 kernel (best verified: 82us attn). Intra-block causal pairing:
// per (b,h), 16 chunks of 128 q rows; block handles (15-p, p) as two phases
// -> identical work per block, robust to undefined block->CU mapping.
// 512 blocks, 4 waves x 32 q rows. K staged via global_load_lds DMA
// (double-buffered, XOR-swizzled source so ds_read_b128 is conflict-free).
// V reg-prefetched then written transposed [d][t pad72], double-buffered.
// (V-layout experiments r4/r6/r7 all regressed; VST=72's 4.3M conflict-cycles
// cost <=5us -- keep.)
// Fixed max: Q pre-scaled by log2e/8 -> p = exp2(s). l via MFMA vs ones.
__device__ __forceinline__ void stage_k(const short* __restrict__ Kb, int t,
                                        short* sbuf, int wid, int lane) {
  // LDS linear dest; source granule XOR-swizzled: LDS[row][j] = K[row][j^(row&7)]
#pragma unroll
  for (int i = 0; i < 2; ++i) {
    int g = wid * 128 + i * 64 + lane;      // 16B granule index, 512 total
    int row = g >> 3;
    int sg = (g & 7) ^ (row & 7);
    const short* gp = Kb + (size_t)(t * 64 + row) * 64 + sg * 8;
    __builtin_amdgcn_global_load_lds(
        (const __attribute__((address_space(1))) void*)gp,
        (__attribute__((address_space(3))) void*)(sbuf + wid * 1024 + i * 512),
        16, 0, 0);
  }
}

__global__ __launch_bounds__(256, 4) void attn_fa(
    const short* __restrict__ Q, const short* __restrict__ K,
    const short* __restrict__ V, short* __restrict__ Aout) {
  __shared__ __align__(16) short sVt[2][64 * 72];  // 18.4 KB
  __shared__ __align__(16) short sK[2][64 * 64];   // 16 KB
  const int tid = threadIdx.x;
  const int lane = tid & 63, wid = tid >> 6;
  const int quad = lane >> 4, ln15 = lane & 15;
  const int e3 = ln15 & 7;
  const int bx = blockIdx.x;
  const int bh = bx & 63;  // bh-minor: all blocks of a bh land on one XCD's L2
  const int p = bx >> 6;   // 0..7
  const short* Qb = Q + (size_t)bh * 131072;
  const short* Kb = K + (size_t)bh * 131072;
  const short* Vb = V + (size_t)bh * 131072;
  const int b = bh >> 4, h = bh & 15;
  const int tp = tid & 31, dgrp = tid >> 5;  // V staging: t=2tp,2tp+1; d0=dgrp*4

  for (int ph = 0; ph < 2; ++ph) {
    const int c = ph ? p : (15 - p);         // chunk id (128 q rows)
    const int nkv = 2 * c + 2;               // uniform barrier count
    const int ntw = 2 * c + 1 + (wid >> 1);  // this wave's live tiles
    const int qw = c * 128 + wid * 32;       // this wave's 32 q rows

    // Q fragments for this chunk
    s16x8 qf[2][2];
#pragma unroll
    for (int qo = 0; qo < 2; ++qo)
#pragma unroll
      for (int ks = 0; ks < 2; ++ks)
        qf[qo][ks] =
            *(const s16x8*)&Qb[(qw + qo * 16 + ln15) * 64 + ks * 32 + quad * 8];

    f32x4 o[2][4] = {};
    f32x4 lacc[2] = {};

    __syncthreads();  // prior phase's LDS reads done before restaging
    // stage V tile 0 -> buf 0 (transposed, packed b32 writes)
#pragma unroll
    for (int i = 0; i < 2; ++i) {
      int d0 = dgrp * 4 + i * 32;
      s16x4 va0 = *(const s16x4*)&Vb[(2 * tp) * 64 + d0];
      s16x4 vb0 = *(const s16x4*)&Vb[(2 * tp + 1) * 64 + d0];
#pragma unroll
      for (int u = 0; u < 4; ++u) {
        unsigned w = (unsigned)(unsigned short)va0[u] |
                     ((unsigned)(unsigned short)vb0[u] << 16);
        *(unsigned*)&sVt[0][(d0 + u) * 72 + 2 * tp] = w;
      }
    }
    // DMA K tile 0 -> buf 0 (drained by first in-loop barrier)
    stage_k(Kb, 0, sK[0], wid, lane);

    for (int kt = 0; kt < nkv; ++kt) {
      __syncthreads();  // drains K DMA (vmcnt0) + makes V writes visible
      const short* bufc = sVt[kt & 1];
      const short* kbuf = sK[kt & 1];
      const bool nxt = (kt + 1 < nkv);
      // prefetch next V tile into regs + DMA next K tile
      s16x4 va[2], vbr[2];
      if (nxt) {
#pragma unroll
        for (int i = 0; i < 2; ++i) {
          int d0 = dgrp * 4 + i * 32;
          va[i] = *(const s16x4*)&Vb[((kt + 1) * 64 + 2 * tp) * 64 + d0];
          vbr[i] = *(const s16x4*)&Vb[((kt + 1) * 64 + 2 * tp + 1) * 64 + d0];
        }
        stage_k(Kb, kt + 1, sK[(kt + 1) & 1], wid, lane);
      }
      if (kt < ntw) {
        __builtin_amdgcn_s_setprio(1);
        // ---- S^T = K Q^T (K from swizzled LDS) ----
        f32x4 s[2][4] = {};
#pragma unroll
        for (int jm = 0; jm < 4; ++jm) {
          const short* kr = &kbuf[(jm * 16 + ln15) * 64];
          s16x8 k0 = *(const s16x8*)&kr[(quad ^ e3) * 8];
          s16x8 k1 = *(const s16x8*)&kr[((4 + quad) ^ e3) * 8];
          s[0][jm] = mfma32(k0, qf[0][0], s[0][jm]);
          s[0][jm] = mfma32(k1, qf[0][1], s[0][jm]);
          s[1][jm] = mfma32(k0, qf[1][0], s[1][jm]);
          s[1][jm] = mfma32(k1, qf[1][1], s[1][jm]);
        }
        __builtin_amdgcn_s_setprio(0);
        // ---- causal mask (diagonal tile only) ----
        if (kt == ntw - 1) {
#pragma unroll
          for (int qo = 0; qo < 2; ++qo) {
            int qg = qw + qo * 16 + ln15;
#pragma unroll
            for (int jm = 0; jm < 4; ++jm) {
              int kg = kt * 64 + jm * 16 + quad * 4;
#pragma unroll
              for (int r = 0; r < 4; ++r)
                if (kg + r > qg) s[qo][jm][r] = -3e38f;
            }
          }
        }
        // ---- p = exp2(s), pack via v_perm ----
        s16x4 pk[2][4];
#pragma unroll
        for (int qo = 0; qo < 2; ++qo)
#pragma unroll
          for (int jm = 0; jm < 4; ++jm) {
            float p0 = __builtin_amdgcn_exp2f(s[qo][jm][0]);
            float p1 = __builtin_amdgcn_exp2f(s[qo][jm][1]);
            float p2 = __builtin_amdgcn_exp2f(s[qo][jm][2]);
            float p3 = __builtin_amdgcn_exp2f(s[qo][jm][3]);
            u32x2 w2;
            w2[0] = pkb(p0, p1);
            w2[1] = pkb(p2, p3);
            pk[qo][jm] = __builtin_bit_cast(s16x4, w2);
          }
        // ---- O += P V; l += P 1 (both MFMA) ----
        __builtin_amdgcn_s_setprio(1);
#if HAVE_MFMA16
        const s16x4 ones = {16256, 16256, 16256, 16256};  // bf16 1.0
#pragma unroll
        for (int js = 0; js < 4; ++js) {
          lacc[0] = mfma16(pk[0][js], ones, lacc[0]);
          lacc[1] = mfma16(pk[1][js], ones, lacc[1]);
#pragma unroll
          for (int jd = 0; jd < 4; ++jd) {
            s16x4 vf =
                *(const s16x4*)&bufc[(jd * 16 + ln15) * 72 + js * 16 + quad * 4];
            o[0][jd] = mfma16(pk[0][js], vf, o[0][jd]);
            o[1][jd] = mfma16(pk[1][js], vf, o[1][jd]);
          }
        }
#else
        const s16x8 ones8 = {16256, 16256, 16256, 16256,
                             16256, 16256, 16256, 16256};
#pragma unroll
        for (int ks = 0; ks < 2; ++ks) {
          s16x8 a0 = repack(pk[0][2 * ks], pk[0][2 * ks + 1], quad, ln15);
          s16x8 a1 = repack(pk[1][2 * ks], pk[1][2 * ks + 1], quad, ln15);
          lacc[0] = mfma32(a0, ones8, lacc[0]);
          lacc[1] = mfma32(a1, ones8, lacc[1]);
#pragma unroll
          for (int jd = 0; jd < 4; ++jd) {
            s16x8 vf =
                *(const s16x8*)&bufc[(jd * 16 + ln15) * 72 + ks * 32 + quad * 8];
            o[0][jd] = mfma32(a0, vf, o[0][jd]);
            o[1][jd] = mfma32(a1, vf, o[1][jd]);
          }
        }
#endif
        __builtin_amdgcn_s_setprio(0);
      }
      // write prefetched V tile -> other buffer
      if (nxt) {
        short* bufn = sVt[(kt + 1) & 1];
#pragma unroll
        for (int i = 0; i < 2; ++i) {
          int d0 = dgrp * 4 + i * 32;
#pragma unroll
          for (int u = 0; u < 4; ++u) {
            unsigned w = (unsigned)(unsigned short)va[i][u] |
                         ((unsigned)(unsigned short)vbr[i][u] << 16);
            *(unsigned*)&bufn[(d0 + u) * 72 + 2 * tp] = w;
          }
        }
      }
    }
    // epilogue: rows q=quad*4+r, cols d=jd*16+ln15; l per-lane from lacc
#pragma unroll
    for (int qo = 0; qo < 2; ++qo)
#pragma unroll
      for (int r = 0; r < 4; ++r) {
        float linv = 1.f / lacc[qo][r];
        int qg = qw + qo * 16 + quad * 4 + r;
        size_t row = ((size_t)b * 2048 + qg) * 1024 + h * 64;
#pragma unroll
        for (int jd = 0; jd < 4; ++jd)
          Aout[row + jd * 16 + ln15] = f2b(o[qo][jd][r] * linv);
      }
  }
}

extern "C" void kernel_launch(void* const* d_in, const int* in_sizes, int n_in,
                              void* d_out, int out_size, void* d_ws, size_t ws_size,
                              hipStream_t stream) {
  const float* x  = (const float*)d_in[0];
  const float* wq = (const float*)d_in[1];
  const float* wk = (const float*)d_in[2];
  const float* wv = (const float*)d_in[3];
  const float* wo = (const float*)d_in[4];
  char* ws = (char*)d_ws;
  short* xb    = (short*)(ws);
  short* wqkvb = (short*)(ws + 16777216);
  short* wob   = (short*)(ws + 23068672);
  short* qkv   = (short*)(ws + 25165824);
  short* attn  = xb;  // x dead after QKV GEMM

  convert_all<<<12288, 256, 0, stream>>>(x, wq, wk, wv, wo, xb, wqkvb, wob);
  gemm_bt<0><<<dim3(24, 128), 256, 0, stream>>>(xb, wqkvb, nullptr, qkv,
                                                8192, 3072, 1024);
  attn_fa<<<512, 256, 0, stream>>>(qkv, qkv + 8388608, qkv + 16777216, attn);
  gemm_bt<1><<<dim3(8, 128), 256, 0, stream>>>(attn, wob, (float*)d_out, nullptr,
                                               8192, 1024, 1024);
}

// Round 10
// 256.250 us; speedup vs baseline: 1.0304x; 1.0304x over previous
//
#include <hip/hip_runtime.h>

typedef __attribute__((ext_vector_type(8))) short s16x8;
typedef __attribute__((ext_vector_type(4))) short s16x4;
typedef __attribute__((ext_vector_type(4))) float f32x4;
typedef __attribute__((ext_vector_type(8))) __bf16 bf16x8;
typedef __attribute__((ext_vector_type(2))) unsigned u32x2;
typedef __attribute__((ext_vector_type(2))) unsigned long long u64x2;

// fp32 -> bf16 round-to-nearest-even
__device__ __forceinline__ short f2b(float f) {
  unsigned u = __float_as_uint(f);
  u += 0x7fffu + ((u >> 16) & 1u);
  return (short)(u >> 16);
}

// pack two fp32 -> two bf16 (truncate) in ONE v_perm_b32
__device__ __forceinline__ unsigned pkb(float lo, float hi) {
  return __builtin_amdgcn_perm(__float_as_uint(hi), __float_as_uint(lo),
                               0x07060302u);
}

__device__ __forceinline__ f32x4 mfma32(s16x8 a, s16x8 b, f32x4 c) {
  return __builtin_amdgcn_mfma_f32_16x16x32_bf16(
      __builtin_bit_cast(bf16x8, a), __builtin_bit_cast(bf16x8, b), c, 0, 0, 0);
}

#if __has_builtin(__builtin_amdgcn_mfma_f32_16x16x16bf16_1k)
#define HAVE_MFMA16 1
__device__ __forceinline__ f32x4 mfma16(s16x4 a, s16x4 b, f32x4 c) {
  return __builtin_amdgcn_mfma_f32_16x16x16bf16_1k(a, b, c, 0, 0, 0);
}
#else
#define HAVE_MFMA16 0
// repack P (S^T C-layout regs, k=16j+quad*4+r) into 16x16x32 A-frag (k=quad*8+c)
__device__ __forceinline__ s16x8 repack(s16x4 pa, s16x4 pb, int quad, int ln15) {
  unsigned long long a = __builtin_bit_cast(unsigned long long, pa);
  unsigned long long bq = __builtin_bit_cast(unsigned long long, pb);
  int srcLo = ((quad & 1) << 5) | ln15;
  unsigned long long loa = __shfl(a, srcLo);
  unsigned long long lob = __shfl(bq, srcLo);
  unsigned long long hia = __shfl(a, srcLo + 16);
  unsigned long long hib = __shfl(bq, srcLo + 16);
  u64x2 t;
  t[0] = quad < 2 ? loa : lob;
  t[1] = quad < 2 ? hia : hib;
  return __builtin_bit_cast(s16x8, t);
}
#endif

// ---------------- convert fp32 -> bf16 (x, Wq|Wk|Wv concat, Wo) ----------------
__global__ __launch_bounds__(256) void convert_all(
    const float* __restrict__ x, const float* __restrict__ wq,
    const float* __restrict__ wk, const float* __restrict__ wv,
    const float* __restrict__ wo, short* __restrict__ xb,
    short* __restrict__ wqkvb, short* __restrict__ wob) {
  size_t i4 = ((size_t)blockIdx.x * 256 + threadIdx.x) * 4;
  const float* src;
  short* dst;
  size_t off;
  if (i4 < 8388608) {
    src = x; dst = xb; off = i4;
  } else if (i4 < 9437184) {
    src = wq; dst = wqkvb; off = i4 - 8388608;
  } else if (i4 < 10485760) {
    src = wk; dst = wqkvb + 1048576; off = i4 - 9437184;
  } else if (i4 < 11534336) {
    src = wv; dst = wqkvb + 2097152; off = i4 - 10485760;
  } else {
    src = wo; dst = wob; off = i4 - 11534336;
  }
  float4 f = *(const float4*)(src + off);
  s16x4 o;
  o[0] = f2b(f.x); o[1] = f2b(f.y); o[2] = f2b(f.z); o[3] = f2b(f.w);
  *(s16x4*)(dst + off) = o;
}

// ---------------- GEMM: C[M,N] = A[M,K] * B[N,K]^T -------------------------
// BK=64, XOR-swizzled staging (r8-verified). EPI 0 (QKV): 128x128 tiles,
// grid 1536, 4 blocks/CU streaming -- byte-identical to r8's K-loop.
// EPI 1 (proj): 128x64 tiles -> grid 1024 = exactly 4 blocks/CU one full
// round (r8's 512 blocks left half the wave slots empty); LDS 24KB,
// acc[4][2]=32 VGPR. Same accumulation order -> bit-identical output.
template <int NITER>
__device__ __forceinline__ void stage_half(const short* __restrict__ g, int ld,
                                           int row0, int k0, short* lds,
                                           int wid, int lane) {
  // NITER*256 granules of 16B; LDS linear dest, source granule XOR-swizzled:
  // LDS[row][j] = G[row][j^(row&7)]
#pragma unroll
  for (int i = 0; i < NITER; ++i) {
    int gr = i * 256 + wid * 64 + lane;
    int row = gr >> 3;
    int sg = (gr & 7) ^ (row & 7);
    const short* gp = g + (size_t)(row0 + row) * ld + k0 + sg * 8;
    __builtin_amdgcn_global_load_lds(
        (const __attribute__((address_space(1))) void*)gp,
        (__attribute__((address_space(3))) void*)(lds + i * 2048 + wid * 512),
        16, 0, 0);
  }
}

// EPI 0: scatter QKV -> Q (pre-scaled by log2e/8), K, V, all bf16 [B,H,T,D],
//        via LDS-coalesced epilogue (16B contiguous stores).
// EPI 1: fp32 direct store.
template <int EPI>
__global__ __launch_bounds__(256) void gemm_bt(
    const short* __restrict__ A, const short* __restrict__ Bw,
    float* __restrict__ outf, short* __restrict__ qkv,
    int M, int N, int K) {
  constexpr int BN = EPI ? 64 : 128;  // N-tile
  constexpr int NJ = BN / 32;         // per-wave N fragments
  // EPI0: staging 32KB, epilogue overlay 128x132 shorts (33792B)
  // EPI1: staging 24KB (lA 16KB + lB 8KB)
  __shared__ __align__(16) char smem[EPI == 0 ? 128 * 132 * 2 : 24576];
  short* lA = (short*)smem;
  short* lB = lA + 8192;
  const int tid = threadIdx.x;
  const int lane = tid & 63, wid = tid >> 6;
  const int quad = lane >> 4, ln15 = lane & 15;
  const int kx = ln15 & 7;  // staging-swizzle read key
  const int wm = wid & 1, wn = wid >> 1;
  // XCD-contiguous tile remap (bijective; nwg divisible by 8)
  const int gx = (int)gridDim.x;
  const int lin = (int)blockIdx.y * gx + (int)blockIdx.x;
  const int cpx = (gx * (int)gridDim.y) >> 3;
  const int t = (lin & 7) * cpx + (lin >> 3);
  const int m0 = (t / gx) * 128, n0 = (t % gx) * BN;

  f32x4 acc[4][NJ] = {};

  stage_half<4>(A, K, m0, 0, lA, wid, lane);
  stage_half<BN / 32>(Bw, K, n0, 0, lB, wid, lane);

  const int nk = K >> 6;
  for (int kt = 0; kt < nk; ++kt) {
    __syncthreads();
#pragma unroll
    for (int h = 0; h < 2; ++h) {
      s16x8 af[4], bf[NJ];
#pragma unroll
      for (int i = 0; i < 4; ++i)
        af[i] = *(const s16x8*)&lA[(wm * 64 + i * 16 + ln15) * 64 +
                                   (((h << 2) + quad) ^ kx) * 8];
#pragma unroll
      for (int j = 0; j < NJ; ++j)
        bf[j] = *(const s16x8*)&lB[(wn * (BN / 2) + j * 16 + ln15) * 64 +
                                   (((h << 2) + quad) ^ kx) * 8];
#pragma unroll
      for (int i = 0; i < 4; ++i)
#pragma unroll
        for (int j = 0; j < NJ; ++j)
          acc[i][j] = mfma32(af[i], bf[j], acc[i][j]);
    }
    __syncthreads();
    if (kt + 1 < nk) {
      stage_half<4>(A, K, m0, (kt + 1) << 6, lA, wid, lane);
      stage_half<BN / 32>(Bw, K, n0, (kt + 1) << 6, lB, wid, lane);
    }
  }

  if (EPI == 1) {
#pragma unroll
    for (int i = 0; i < 4; ++i)
#pragma unroll
      for (int j = 0; j < NJ; ++j)
#pragma unroll
        for (int r = 0; r < 4; ++r) {
          int m = m0 + wm * 64 + i * 16 + quad * 4 + r;
          int n = n0 + wn * (BN / 2) + j * 16 + ln15;
          outf[(size_t)m * N + n] = acc[i][j][r];
        }
  } else {
    const float QSC = 0.18033688f;  // (1/sqrt(64)) * log2(e), folded into Q
    const int which = n0 >> 10;     // whole 128-tile within one of Q/K/V
    const float sf = (which == 0) ? QSC : 1.0f;
    short* lC = (short*)smem;
    __syncthreads();  // all waves done with lA/lB ds_reads
#pragma unroll
    for (int i = 0; i < 4; ++i)
#pragma unroll
      for (int j = 0; j < NJ; ++j) {
        int mm = wm * 64 + i * 16 + quad * 4;
        int nn = wn * (BN / 2) + j * 16 + ln15;
#pragma unroll
        for (int r = 0; r < 4; ++r)
          lC[(mm + r) * 132 + nn] = f2b(acc[i][j][r] * sf);
      }
    __syncthreads();
    short* outb = qkv + (size_t)which * 8388608;
#pragma unroll
    for (int r0 = 0; r0 < 8; ++r0) {
      int m = r0 * 16 + (tid >> 4);
      int ncol = (tid & 15) * 8;
      s16x4 lo = *(const s16x4*)&lC[m * 132 + ncol];
      s16x4 hi = *(const s16x4*)&lC[m * 132 + ncol + 4];
      s16x8 v8;
#pragma unroll
      for (int z = 0; z < 4; ++z) { v8[z] = lo[z]; v8[4 + z] = hi[z]; }
      int n = n0 + ncol;
      int mg = m0 + m;
      int bidx = mg >> 11, tt = mg & 2047;
      int hh = (n >> 6) & 15, d0 = n & 63;
      *(s16x8*)&outb[(size_t)((((bidx << 4) + hh) << 11) + tt) * 64 + d0] = v8;
    }
  }
}

// ---------------- flash attention, S^T form, fixed-max ----------------------
// EXACT r3 kernel (best verified: 82us attn). Intra-block causal pairing:
// per (b,h), 16 chunks of 128 q rows; block handles (15-p, p) as two phases
// -> identical work per block, robust to undefined block->CU mapping.
// 512 blocks, 4 waves x 32 q rows. K staged via global_load_lds DMA
// (double-buffered, XOR-swizzled source so ds_read_b128 is conflict-free).
// V reg-prefetched then written transposed [d][t pad72], double-buffered.
// (V-layout experiments r4/r6/r7 all regressed; VST=72's 4.3M conflict-cycles
// cost <=5us -- keep.)
// Fixed max: Q pre-scaled by log2e/8 -> p = exp2(s). l via MFMA vs ones.
__device__ __forceinline__ void stage_k(const short* __restrict__ Kb, int t,
                                        short* sbuf, int wid, int lane) {
  // LDS linear dest; source granule XOR-swizzled: LDS[row][j] = K[row][j^(row&7)]
#pragma unroll
  for (int i = 0; i < 2; ++i) {
    int g = wid * 128 + i * 64 + lane;      // 16B granule index, 512 total
    int row = g >> 3;
    int sg = (g & 7) ^ (row & 7);
    const short* gp = Kb + (size_t)(t * 64 + row) * 64 + sg * 8;
    __builtin_amdgcn_global_load_lds(
        (const __attribute__((address_space(1))) void*)gp,
        (__attribute__((address_space(3))) void*)(sbuf + wid * 1024 + i * 512),
        16, 0, 0);
  }
}

__global__ __launch_bounds__(256, 4) void attn_fa(
    const short* __restrict__ Q, const short* __restrict__ K,
    const short* __restrict__ V, short* __restrict__ Aout) {
  __shared__ __align__(16) short sVt[2][64 * 72];  // 18.4 KB
  __shared__ __align__(16) short sK[2][64 * 64];   // 16 KB
  const int tid = threadIdx.x;
  const int lane = tid & 63, wid = tid >> 6;
  const int quad = lane >> 4, ln15 = lane & 15;
  const int e3 = ln15 & 7;
  const int bx = blockIdx.x;
  const int bh = bx & 63;  // bh-minor: all blocks of a bh land on one XCD's L2
  const int p = bx >> 6;   // 0..7
  const short* Qb = Q + (size_t)bh * 131072;
  const short* Kb = K + (size_t)bh * 131072;
  const short* Vb = V + (size_t)bh * 131072;
  const int b = bh >> 4, h = bh & 15;
  const int tp = tid & 31, dgrp = tid >> 5;  // V staging: t=2tp,2tp+1; d0=dgrp*4

  for (int ph = 0; ph < 2; ++ph) {
    const int c = ph ? p : (15 - p);         // chunk id (128 q rows)
    const int nkv = 2 * c + 2;               // uniform barrier count
    const int ntw = 2 * c + 1 + (wid >> 1);  // this wave's live tiles
    const int qw = c * 128 + wid * 32;       // this wave's 32 q rows

    // Q fragments for this chunk
    s16x8 qf[2][2];
#pragma unroll
    for (int qo = 0; qo < 2; ++qo)
#pragma unroll
      for (int ks = 0; ks < 2; ++ks)
        qf[qo][ks] =
            *(const s16x8*)&Qb[(qw + qo * 16 + ln15) * 64 + ks * 32 + quad * 8];

    f32x4 o[2][4] = {};
    f32x4 lacc[2] = {};

    __syncthreads();  // prior phase's LDS reads done before restaging
    // stage V tile 0 -> buf 0 (transposed, packed b32 writes)
#pragma unroll
    for (int i = 0; i < 2; ++i) {
      int d0 = dgrp * 4 + i * 32;
      s16x4 va0 = *(const s16x4*)&Vb[(2 * tp) * 64 + d0];
      s16x4 vb0 = *(const s16x4*)&Vb[(2 * tp + 1) * 64 + d0];
#pragma unroll
      for (int u = 0; u < 4; ++u) {
        unsigned w = (unsigned)(unsigned short)va0[u] |
                     ((unsigned)(unsigned short)vb0[u] << 16);
        *(unsigned*)&sVt[0][(d0 + u) * 72 + 2 * tp] = w;
      }
    }
    // DMA K tile 0 -> buf 0 (drained by first in-loop barrier)
    stage_k(Kb, 0, sK[0], wid, lane);

    for (int kt = 0; kt < nkv; ++kt) {
      __syncthreads();  // drains K DMA (vmcnt0) + makes V writes visible
      const short* bufc = sVt[kt & 1];
      const short* kbuf = sK[kt & 1];
      const bool nxt = (kt + 1 < nkv);
      // prefetch next V tile into regs + DMA next K tile
      s16x4 va[2], vbr[2];
      if (nxt) {
#pragma unroll
        for (int i = 0; i < 2; ++i) {
          int d0 = dgrp * 4 + i * 32;
          va[i] = *(const s16x4*)&Vb[((kt + 1) * 64 + 2 * tp) * 64 + d0];
          vbr[i] = *(const s16x4*)&Vb[((kt + 1) * 64 + 2 * tp + 1) * 64 + d0];
        }
        stage_k(Kb, kt + 1, sK[(kt + 1) & 1], wid, lane);
      }
      if (kt < ntw) {
        __builtin_amdgcn_s_setprio(1);
        // ---- S^T = K Q^T (K from swizzled LDS) ----
        f32x4 s[2][4] = {};
#pragma unroll
        for (int jm = 0; jm < 4; ++jm) {
          const short* kr = &kbuf[(jm * 16 + ln15) * 64];
          s16x8 k0 = *(const s16x8*)&kr[(quad ^ e3) * 8];
          s16x8 k1 = *(const s16x8*)&kr[((4 + quad) ^ e3) * 8];
          s[0][jm] = mfma32(k0, qf[0][0], s[0][jm]);
          s[0][jm] = mfma32(k1, qf[0][1], s[0][jm]);
          s[1][jm] = mfma32(k0, qf[1][0], s[1][jm]);
          s[1][jm] = mfma32(k1, qf[1][1], s[1][jm]);
        }
        __builtin_amdgcn_s_setprio(0);
        // ---- causal mask (diagonal tile only) ----
        if (kt == ntw - 1) {
#pragma unroll
          for (int qo = 0; qo < 2; ++qo) {
            int qg = qw + qo * 16 + ln15;
#pragma unroll
            for (int jm = 0; jm < 4; ++jm) {
              int kg = kt * 64 + jm * 16 + quad * 4;
#pragma unroll
              for (int r = 0; r < 4; ++r)
                if (kg + r > qg) s[qo][jm][r] = -3e38f;
            }
          }
        }
        // ---- p = exp2(s), pack via v_perm ----
        s16x4 pk[2][4];
#pragma unroll
        for (int qo = 0; qo < 2; ++qo)
#pragma unroll
          for (int jm = 0; jm < 4; ++jm) {
            float p0 = __builtin_amdgcn_exp2f(s[qo][jm][0]);
            float p1 = __builtin_amdgcn_exp2f(s[qo][jm][1]);
            float p2 = __builtin_amdgcn_exp2f(s[qo][jm][2]);
            float p3 = __builtin_amdgcn_exp2f(s[qo][jm][3]);
            u32x2 w2;
            w2[0] = pkb(p0, p1);
            w2[1] = pkb(p2, p3);
            pk[qo][jm] = __builtin_bit_cast(s16x4, w2);
          }
        // ---- O += P V; l += P 1 (both MFMA) ----
        __builtin_amdgcn_s_setprio(1);
#if HAVE_MFMA16
        const s16x4 ones = {16256, 16256, 16256, 16256};  // bf16 1.0
#pragma unroll
        for (int js = 0; js < 4; ++js) {
          lacc[0] = mfma16(pk[0][js], ones, lacc[0]);
          lacc[1] = mfma16(pk[1][js], ones, lacc[1]);
#pragma unroll
          for (int jd = 0; jd < 4; ++jd) {
            s16x4 vf =
                *(const s16x4*)&bufc[(jd * 16 + ln15) * 72 + js * 16 + quad * 4];
            o[0][jd] = mfma16(pk[0][js], vf, o[0][jd]);
            o[1][jd] = mfma16(pk[1][js], vf, o[1][jd]);
          }
        }
#else
        const s16x8 ones8 = {16256, 16256, 16256, 16256,
                             16256, 16256, 16256, 16256};
#pragma unroll
        for (int ks = 0; ks < 2; ++ks) {
          s16x8 a0 = repack(pk[0][2 * ks], pk[0][2 * ks + 1], quad, ln15);
          s16x8 a1 = repack(pk[1][2 * ks], pk[1][2 * ks + 1], quad, ln15);
          lacc[0] = mfma32(a0, ones8, lacc[0]);
          lacc[1] = mfma32(a1, ones8, lacc[1]);
#pragma unroll
          for (int jd = 0; jd < 4; ++jd) {
            s16x8 vf =
                *(const s16x8*)&bufc[(jd * 16 + ln15) * 72 + ks * 32 + quad * 8];
            o[0][jd] = mfma32(a0, vf, o[0][jd]);
            o[1][jd] = mfma32(a1, vf, o[1][jd]);
          }
        }
#endif
        __builtin_amdgcn_s_setprio(0);
      }
      // write prefetched V tile -> other buffer
      if (nxt) {
        short* bufn = sVt[(kt + 1) & 1];
#pragma unroll
        for (int i = 0; i < 2; ++i) {
          int d0 = dgrp * 4 + i * 32;
#pragma unroll
          for (int u = 0; u < 4; ++u) {
            unsigned w = (unsigned)(unsigned short)va[i][u] |
                         ((unsigned)(unsigned short)vbr[i][u] << 16);
            *(unsigned*)&bufn[(d0 + u) * 72 + 2 * tp] = w;
          }
        }
      }
    }
    // epilogue: rows q=quad*4+r, cols d=jd*16+ln15; l per-lane from lacc
#pragma unroll
    for (int qo = 0; qo < 2; ++qo)
#pragma unroll
      for (int r = 0; r < 4; ++r) {
        float linv = 1.f / lacc[qo][r];
        int qg = qw + qo * 16 + quad * 4 + r;
        size_t row = ((size_t)b * 2048 + qg) * 1024 + h * 64;
#pragma unroll
        for (int jd = 0; jd < 4; ++jd)
          Aout[row + jd * 16 + ln15] = f2b(o[qo][jd][r] * linv);
      }
  }
}

extern "C" void kernel_launch(void* const* d_in, const int* in_sizes, int n_in,
                              void* d_out, int out_size, void* d_ws, size_t ws_size,
                              hipStream_t stream) {
  const float* x  = (const float*)d_in[0];
  const float* wq = (const float*)d_in[1];
  const float* wk = (const float*)d_in[2];
  const float* wv = (const float*)d_in[3];
  const float* wo = (const float*)d_in[4];
  char* ws = (char*)d_ws;
  short* xb    = (short*)(ws);
  short* wqkvb = (short*)(ws + 16777216);
  short* wob   = (short*)(ws + 23068672);
  short* qkv   = (short*)(ws + 25165824);
  short* attn  = xb;  // x dead after QKV GEMM

  convert_all<<<12288, 256, 0, stream>>>(x, wq, wk, wv, wo, xb, wqkvb, wob);
  gemm_bt<0><<<dim3(24, 64), 256, 0, stream>>>(xb, wqkvb, nullptr, qkv,
                                               8192, 3072, 1024);
  attn_fa<<<512, 256, 0, stream>>>(qkv, qkv + 8388608, qkv + 16777216, attn);
  gemm_bt<1><<<dim3(16, 64), 256, 0, stream>>>(attn, wob, (float*)d_out, nullptr,
                                               8192, 1024, 1024);
}